// Round 4
// baseline (12108.266 us; speedup 1.0000x reference)
//
#include <hip/hip_runtime.h>

// LSTM layer. Inputs f32, OUTPUT f32 (reference output dtype is float32 —
// the harness label "(bf16, ...)" is a hardcoded string; R2/R3 bit-identical
// errors were the bf16-pair-packed-into-f32 artifact).
//
// Phase A (parallel): x_gates[t,b,:] = W_ih·x[t,b] + b_ih + b_hh  (f32)
// Phase B (persistent, 256 wgs = 1/CU): wg=(batch b, quarter q); each thread
//   holds one W_hh row in VGPRs (256 f32). Per-step h exchange between a
//   batch's 4 wgs via 64-bit tagged words (tag<<32 | f32 bits) — single-atom,
//   no fence — parity double-buffered for back-pressure. c in VGPRs, f32.
// T chunked by ws capacity; h crosses chunks through the exchange (tags are
// global t), c through a ws state region.

#define TT 2048
#define BB 64
#define HH 256
#define GG 1024  // 4H

// ws layout
#define EXCH_OFF 0         // 64 x 2 x 256 x 8B = 256 KiB
#define CST_OFF 0x40000    // 64 x 256 f32 = 64 KiB
#define XG_OFF 0x50000     // chunkT*64*1024 f32

__device__ __forceinline__ float sigm(float x) { return 1.0f / (1.0f + __expf(-x)); }
// tanh via __expf; e=inf -> 1, e=0 -> -1 (no inf/inf).
__device__ __forceinline__ float tanh_(float x) {
  float e = __expf(2.0f * x);
  return 1.0f - 2.0f / (e + 1.0f);
}

// ---------------- Phase A: x_gates ----------------
__global__ __launch_bounds__(256, 1) void lstm_xgates(
    const float* __restrict__ xin,  // [T,B,256]
    const float* __restrict__ Wih,  // [1024,256]
    const float* __restrict__ bih, const float* __restrict__ bhh,
    float* __restrict__ xg,  // [ct*64, 1024] (pair-local)
    int t0, int ct)
{
  const int tid = threadIdx.x;
  const int q = blockIdx.x >> 6;    // quarter 0..3
  const int blk = blockIdx.x & 63;  // pair-block 0..63
  const int gt = tid >> 6, u = tid & 63;
  const int row = 256 * gt + 64 * q + u;

  float4 wv[64];
  {
    const float4* wp = (const float4*)(Wih + (size_t)row * HH);
#pragma unroll
    for (int k = 0; k < 64; ++k) wv[k] = wp[k];
  }
  const float bias = bih[row] + bhh[row];

  // this block's pair-local range: [blk*ct, (blk+1)*ct)
  for (int n = 0; n < ct; ++n) {
    const size_t pl = (size_t)blk * ct + n;               // pair-local index
    const float* xp = xin + ((size_t)t0 * BB + pl) * HH;  // wave-uniform
    float a0 = 0.f, a1 = 0.f, a2 = 0.f, a3 = 0.f;
#pragma unroll
    for (int k = 0; k < 64; ++k) {
      a0 = fmaf(wv[k].x, xp[4 * k + 0], a0);
      a1 = fmaf(wv[k].y, xp[4 * k + 1], a1);
      a2 = fmaf(wv[k].z, xp[4 * k + 2], a2);
      a3 = fmaf(wv[k].w, xp[4 * k + 3], a3);
    }
    xg[pl * GG + 256 * q + tid] = ((a0 + a1) + (a2 + a3)) + bias;
  }
}

// ---------------- Phase B: recurrence ----------------
__global__ __launch_bounds__(256, 1) void lstm_rec(
    const float* __restrict__ h0, const float* __restrict__ c0,
    const float* __restrict__ Whh,  // [1024,256]
    const float* __restrict__ xg,   // [ct*64, 1024] pair-local
    float* __restrict__ out,        // f32: [T,B,256] ++ hT ++ cT
    unsigned long long* exch,       // [64][2][256] tagged f32
    float* __restrict__ cstate,     // [64][256]
    int t0, int t1)
{
  const int tid = threadIdx.x;
  const int w = blockIdx.x;
  // XCD-swizzle: a batch's 4 wgs share blockIdx%8 (perf heuristic only).
  const int r = w & 7, q = (w >> 3) & 3, s5 = w >> 5;
  const int b = 8 * s5 + r;  // batch 0..63
  const int gt = tid >> 6, u = tid & 63;
  const int row = 256 * gt + 64 * q + u;

  float4 wv[64];
  {
    const float4* wp = (const float4*)(Whh + (size_t)row * HH);
#pragma unroll
    for (int k = 0; k < 64; ++k) wv[k] = wp[k];
  }

  float cst = 0.f;
  if (tid < 64) {
    const int jj = 64 * q + tid;
    cst = (t0 == 0) ? c0[b * HH + jj] : cstate[b * HH + jj];
  }

  __shared__ __align__(16) float hbf[256];
  __shared__ float gl[256];

  unsigned long long* exb = exch + b * 512;  // 2 parity slots x 256

  // x_gate for t0 (pair-local index (t-t0)*64 + b)
  float xgv = xg[(size_t)b * GG + 256 * q + tid];

  for (int t = t0; t < t1; ++t) {
    // ---- phase 1: h_t -> LDS (f32) ----
    if (t == 0) {
      hbf[tid] = h0[b * HH + tid];
    } else {
      unsigned long long* slot = exb + ((t & 1) << 8) + tid;
      unsigned long long wd;
      do {
        wd = __hip_atomic_load(slot, __ATOMIC_RELAXED, __HIP_MEMORY_SCOPE_AGENT);
      } while ((unsigned int)(wd >> 32) != (unsigned int)t);
      union { unsigned int i; float f; } cv;
      cv.i = (unsigned int)wd;
      hbf[tid] = cv.f;
    }
    __syncthreads();

    // prefetch x_gate for t+1 (hidden under the dot loop)
    float xgn = 0.f;
    if (t + 1 < t1)
      xgn = xg[((size_t)(t + 1 - t0) * BB + b) * GG + 256 * q + tid];

    // ---- phase 2: gate = xg + Whh[row]·h_t (f32) ----
    float a0 = xgv, a1 = 0.f, a2 = 0.f, a3 = 0.f;
    {
      const float4* hq = (const float4*)hbf;
#pragma unroll
      for (int k = 0; k < 64; ++k) {
        float4 hv = hq[k];  // same-address LDS broadcast
        a0 = fmaf(wv[k].x, hv.x, a0);
        a1 = fmaf(wv[k].y, hv.y, a1);
        a2 = fmaf(wv[k].z, hv.z, a2);
        a3 = fmaf(wv[k].w, hv.w, a3);
      }
    }
    gl[tid] = (a0 + a1) + (a2 + a3);
    xgv = xgn;
    __syncthreads();

    // ---- phase 3: elementwise + publish (threads 0..63) ----
    if (tid < 64) {
      const float gi = gl[tid];
      const float gf = gl[64 + tid];
      const float gg = gl[128 + tid];
      const float go = gl[192 + tid];
      const float ig = sigm(gi), fg = sigm(gf), gc = tanh_(gg), og = sigm(go);
      cst = fg * cst + ig * gc;
      const float hv = og * tanh_(cst);
      const int jj = 64 * q + tid;
      out[(size_t)t * (BB * HH) + (size_t)b * HH + jj] = hv;
      union { float f; unsigned int i; } hu;
      hu.f = hv;
      // tag t+1 rides with the f32 payload in one 64-bit word
      __hip_atomic_store(exb + (((t + 1) & 1) << 8) + jj,
                         (((unsigned long long)(unsigned int)(t + 1)) << 32) | hu.i,
                         __ATOMIC_RELAXED, __HIP_MEMORY_SCOPE_AGENT);
      if (t == TT - 1) {
        const size_t base = (size_t)TT * (BB * HH);
        out[base + (size_t)b * HH + jj] = hv;           // h_T
        out[base + BB * HH + (size_t)b * HH + jj] = cst;  // c_T
      }
      if (t == t1 - 1) cstate[b * HH + jj] = cst;
    }
    // gl/hbf rewrites are fenced by the next iteration's barriers.
  }
}

extern "C" void kernel_launch(void* const* d_in, const int* in_sizes, int n_in,
                              void* d_out, int out_size, void* d_ws, size_t ws_size,
                              hipStream_t stream) {
  const float* xin = (const float*)d_in[0];
  const float* h0 = (const float*)d_in[1];
  const float* c0 = (const float*)d_in[2];
  const float* Wih = (const float*)d_in[3];
  const float* Whh = (const float*)d_in[4];
  const float* bih = (const float*)d_in[5];
  const float* bhh = (const float*)d_in[6];
  float* out = (float*)d_out;

  char* ws = (char*)d_ws;
  unsigned long long* exch = (unsigned long long*)(ws + EXCH_OFF);
  float* cstate = (float*)(ws + CST_OFF);
  float* xg = (float*)(ws + XG_OFF);

  // chunk T by available xg space
  size_t avail = (ws_size > XG_OFF) ? (ws_size - XG_OFF) : 0;
  long chunkT = (long)(avail / ((size_t)BB * GG * sizeof(float)));
  if (chunkT > TT) chunkT = TT;
  if (chunkT < 1) chunkT = 1;

  hipMemsetAsync(ws + EXCH_OFF, 0, 0x40000, stream);  // clear exchange tags
  for (int t0 = 0; t0 < TT; t0 += (int)chunkT) {
    int ct = (TT - t0 < chunkT) ? (TT - t0) : (int)chunkT;
    hipLaunchKernelGGL(lstm_xgates, dim3(256), dim3(256), 0, stream,
                       xin, Wih, bih, bhh, xg, t0, ct);
    hipLaunchKernelGGL(lstm_rec, dim3(256), dim3(256), 0, stream,
                       h0, c0, Whh, xg, out, exch, cstate, t0, t0 + ct);
  }
}